// Round 11
// baseline (61.015 us; speedup 1.0000x reference)
//
#include <hip/hip_runtime.h>
#include <hip/hip_bf16.h>
#include <math.h>

// ProbaV cPSNR:  loss(u,v) = E[d^2] - (E[d])^2,  d = ct - pm_window(u,v)
// S1(u,v) = T1 - W1(u,v);  S2(u,v) = T2 - 2*CC(u,v) + W2(u,v)
//   T1,T2   : sum ct, sum ct^2            (ct = target*mask, inner 378x378 @ +3)
//   CC(u,v) : sum ct[r][c] * pm[r+u][c+v] (pm = predict*mask)
//   W1,W2   : window sums of pm, pm^2 over rows [u,u+378) x cols [v,v+378)
// W = Total - BR(u) - BC(v) + X(u,v)  (inclusion-exclusion, rows 0..382 x cols 0..383)
//
// R10: LDS-tiled. One 256-thread block = 32 ct rows x 64 ct cols. pm slab
// (37 x 72, p*m fused) staged ONCE into LDS (~11 global quads/thread vs 82;
// one independent-load round-trip instead of an 8-deep dependent chain).
// R3-R9 evidence: time ~ dependent-load-chain x mem-instrs; occupancy knobs
// saturated at ~14%. Bank-conflict-free pm reads (stride 84: 8 rows -> 8
// distinct bank offsets; seg pairs 2-way = free). XCD swizzle (2368 = 8*296,
// bijective). Two plain dispatches (R5: fence storm).

#define NIMG 32
#define IMGSZ (384 * 384)
#define RB 32                    // ct rows per cc block
#define CB 64                    // ct cols per cc block
#define SR 37                    // pm slab rows (RB + 5)
#define PMS 84                   // pm slab LDS stride in floats (16B-aligned, bank-spread)
#define NRB 12                   // row blocks (last covers rows 352..377)
#define NCB 6                    // col blocks
#define NCCB (NIMG * NRB * NCB)  // 2304
#define NEDGE 64                 // 2 per image
#define NTOT (NCCB + NEDGE)      // 2368 = 8 * 296
#define CHUNK 296
#define NM 40                    // cc[36], t1, t2, tot1, tot2
#define MSTRIDE 2304             // mpart col-major [NM][MSTRIDE]
#define MQUADS 576               // MSTRIDE/4
#define NE 262                   // edge entries per image

__global__ __launch_bounds__(256) void probav_fused_kernel(
    const float* __restrict__ predict,
    const float* __restrict__ target,
    const float* __restrict__ mask,
    float* __restrict__ mpart /* [NM][MSTRIDE] */,
    double* __restrict__ epart /* [NE][NIMG] */) {

  // XCD-chunked swizzle: bijective on 2368 = 8*296.
  const int lbid = (blockIdx.x & 7) * CHUNK + (blockIdx.x >> 3);

  __shared__ float pm_lds[SR * PMS];     // 12432 B
  __shared__ float red[4 * NM];          //   640 B
  __shared__ double shbuf[506];          //  4048 B (edge path)

  const int t = threadIdx.x;
  const int lane = t & 63;
  const int w = t >> 6;

  if (lbid >= NEDGE) {
    // ---------------- cc path ----------------
    const int cb  = lbid - NEDGE;
    const int img = cb / (NRB * NCB);
    const int rem = cb - img * (NRB * NCB);
    const int rb  = rem / NCB;
    const int jcb = rem - rb * NCB;
    const int r0  = rb * RB;             // ct row base
    const int jb0 = jcb * CB;            // ct col base
    const size_t base = (size_t)img * IMGSZ;

    // ---- stage pm slab: rows r0..r0+36, cols jb0..jb0+71 (18 quads/row) ----
    float tot1 = 0.f, tot2 = 0.f;
    const int ownSrMax = (rb == NRB - 1) ? 30 : 31;   // pm universe rows 0..382, owned once
    for (int k = t; k < SR * 18; k += 256) {
      const int row = k / 18;
      const int q   = k - row * 18;
      int grow = r0 + row;  if (grow > 383) grow = 383;   // clamp (garbage-safe: masked consumers)
      int gcol = jb0 + 4 * q; if (gcol > 380) gcol = 380; // stay in-row (jcb=5 halo)
      const float4 a = *reinterpret_cast<const float4*>(predict + base + (size_t)grow * 384 + gcol);
      const float4 b = *reinterpret_cast<const float4*>(mask    + base + (size_t)grow * 384 + gcol);
      float4 p;
      p.x = a.x * b.x; p.y = a.y * b.y; p.z = a.z * b.z; p.w = a.w * b.w;
      *reinterpret_cast<float4*>(&pm_lds[row * PMS + 4 * q]) = p;
      if (row <= ownSrMax && q < 16) {   // owned: 32 (or 31) rows x 64 cols
        tot1 += p.x + p.y + p.z + p.w;
        tot2 = fmaf(p.x, p.x, tot2); tot2 = fmaf(p.y, p.y, tot2);
        tot2 = fmaf(p.z, p.z, tot2); tot2 = fmaf(p.w, p.w, tot2);
      }
    }

    // ---- ct row: direct global loads (3 quads t, 3 quads m) ----
    const int s   = t & 7;               // col seg 0..7
    const int rIn = t >> 3;              // row in tile 0..31
    const int r   = r0 + rIn;            // ct output row (>=378 masked)
    const int jb  = jb0 + 8 * s;
    const bool rowValid = (r < 378);
    const int inRow = rowValid ? (r + 3) : 380;   // clamp keeps quads in-image

    float ct[8];
    float t1 = 0.f, t2 = 0.f;
    {
      const float4* tq = reinterpret_cast<const float4*>(target + base + (size_t)inRow * 384 + jb);
      const float4* mq = reinterpret_cast<const float4*>(mask   + base + (size_t)inRow * 384 + jb);
      float tv[12], mv[12];
#pragma unroll
      for (int q = 0; q < 3; ++q) {
        float4 a = tq[q];
        float4 b = mq[q];
        tv[4 * q + 0] = a.x; tv[4 * q + 1] = a.y; tv[4 * q + 2] = a.z; tv[4 * q + 3] = a.w;
        mv[4 * q + 0] = b.x; mv[4 * q + 1] = b.y; mv[4 * q + 2] = b.z; mv[4 * q + 3] = b.w;
      }
#pragma unroll
      for (int x = 0; x < 8; ++x) {
        float v = tv[3 + x] * mv[3 + x];
        v = (rowValid && (jb + x < 378)) ? v : 0.f;
        ct[x] = v;
        t1 += v;
        t2 = fmaf(v, v, t2);
      }
    }

    __syncthreads();   // pm slab ready

    // ---- cc: 36 offsets from LDS (24 conflict-free b128 reads) ----
    float cc[36];
#pragma unroll
    for (int o = 0; o < 36; ++o) cc[o] = 0.f;
#pragma unroll
    for (int u = 0; u < 6; ++u) {
      const float4* pr = reinterpret_cast<const float4*>(&pm_lds[(rIn + u) * PMS + 8 * s]);
      float pm[16];
#pragma unroll
      for (int q = 0; q < 4; ++q) {
        float4 a = pr[q];
        pm[4 * q + 0] = a.x; pm[4 * q + 1] = a.y; pm[4 * q + 2] = a.z; pm[4 * q + 3] = a.w;
      }
#pragma unroll
      for (int v = 0; v < 6; ++v) {
#pragma unroll
        for (int x = 0; x < 8; ++x) {
          cc[u * 6 + v] = fmaf(ct[x], pm[v + x], cc[u * 6 + v]);
        }
      }
    }

    // ---- block reduction: 40 floats -> mpart column-major ----
#pragma unroll
    for (int o = 0; o < 36; ++o) {
      float a = cc[o];
#pragma unroll
      for (int off = 32; off > 0; off >>= 1) a += __shfl_down(a, off);
      if (lane == 0) red[w * NM + o] = a;
    }
    {
      float a = t1, b = t2, c = tot1, d = tot2;
#pragma unroll
      for (int off = 32; off > 0; off >>= 1) {
        a += __shfl_down(a, off);
        b += __shfl_down(b, off);
        c += __shfl_down(c, off);
        d += __shfl_down(d, off);
      }
      if (lane == 0) { red[w * NM + 36] = a; red[w * NM + 37] = b; red[w * NM + 38] = c; red[w * NM + 39] = d; }
    }
    __syncthreads();
    if (t < NM) {
      mpart[t * MSTRIDE + cb] = red[0 * NM + t] + red[1 * NM + t] +
                                red[2 * NM + t] + red[3 * NM + t];
    }
  } else {
    // ---------------- edge path: 2 blocks per image ----------------
    const int img = lbid >> 1;
    const int slice = lbid & 1;
    const size_t base = (size_t)img * IMGSZ;
    double* sh = shbuf;

    if (slice == 0) {
      // full-row sums, rows {0..4, 378..382}, cols 0..383
      if (t < 250) {
        const int ridx = t / 25, cs = t % 25;
        const int row = (ridx < 5) ? ridx : (373 + ridx);
        const float* pr = predict + base + (size_t)row * 384;
        const float* mr = mask    + base + (size_t)row * 384;
        double e1 = 0.0, e2 = 0.0;
        for (int c = cs; c < 384; c += 25) {
          float v = pr[c] * mr[c];
          e1 += v;
          e2 += (double)v * v;
        }
        sh[ridx * 25 + cs] = e1;
        sh[250 + ridx * 25 + cs] = e2;
      }
      __syncthreads();
      if (t < 20) {
        const int kind = t / 10, ridx = t % 10;
        double s = 0.0;
        for (int k = 0; k < 25; ++k) s += sh[kind * 250 + ridx * 25 + k];
        epart[(size_t)(kind * 10 + ridx) * NIMG + img] = s;
      }
      // corner table 10x11
      if (t < 110) {
        const int ridx = t / 11, cidx = t % 11;
        const int row = (ridx < 5) ? ridx : (373 + ridx);
        const int col = (cidx < 5) ? cidx : (373 + cidx);
        float v = predict[base + (size_t)row * 384 + col] * mask[base + (size_t)row * 384 + col];
        epart[(size_t)(42 + t)  * NIMG + img] = (double)v;
        epart[(size_t)(152 + t) * NIMG + img] = (double)v * v;
      }
    } else {
      // full-col sums, cols {0..4, 378..383}, rows 0..382
      if (t < 253) {
        const int cidx = t / 23, rs = t % 23;
        const int col = (cidx < 5) ? cidx : (373 + cidx);
        double f1 = 0.0, f2 = 0.0;
        for (int r = rs; r < 383; r += 23) {
          float v = predict[base + (size_t)r * 384 + col] * mask[base + (size_t)r * 384 + col];
          f1 += v;
          f2 += (double)v * v;
        }
        sh[cidx * 23 + rs] = f1;
        sh[253 + cidx * 23 + rs] = f2;
      }
      __syncthreads();
      if (t < 22) {
        const int kind = t / 11, cidx = t % 11;
        double s = 0.0;
        for (int k = 0; k < 23; ++k) s += sh[kind * 253 + cidx * 23 + k];
        epart[(size_t)(20 + kind * 11 + cidx) * NIMG + img] = s;
      }
    }
  }
}

// ---------------- final kernel: assemble 36 losses, min, score ----------------
__global__ void probav_final_kernel(const float* __restrict__ mpart,
                                    const double* __restrict__ epart,
                                    float* __restrict__ out) {
  __shared__ double M[NM];
  __shared__ double E[NE];
  __shared__ double Etmp[524];
  __shared__ double loss[36];
  const int t = threadIdx.x;          // 1024 threads
  const int lane = t & 63;
  const int w = t >> 6;               // 16 waves

  // M: 40 columns; each column is MSTRIDE contiguous floats = MQUADS float4s
  for (int v = w; v < NM; v += 16) {
    const float4* qp = reinterpret_cast<const float4*>(mpart + v * MSTRIDE);
    double s = 0.0;
    for (int i = lane; i < MQUADS; i += 64) {
      float4 q = qp[i];
      s += (double)q.x + (double)q.y + (double)q.z + (double)q.w;
    }
#pragma unroll
    for (int off = 32; off > 0; off >>= 1) s += __shfl_down(s, off);
    if (lane == 0) M[v] = s;
  }
  // E: 262 entries x 32 contiguous doubles, 2 threads per entry
  if (t < 524) {
    const int e = t >> 1, si = t & 1;
    double s = 0.0;
    for (int i = si * 16; i < si * 16 + 16; ++i) s += epart[(size_t)e * NIMG + i];
    Etmp[t] = s;
  }
  __syncthreads();
  if (t < NE) E[t] = Etmp[2 * t] + Etmp[2 * t + 1];
  __syncthreads();

  if (t < 36) {
    const int u = t / 6, v = t % 6;
    double br1 = 0, br2 = 0, bc1 = 0, bc2 = 0, x1 = 0, x2 = 0;
    int rset[5], nr = 0;
    for (int j = 0; j < u; ++j) rset[nr++] = j;
    for (int j = 5 + u; j < 10; ++j) rset[nr++] = j;
    int cset[6], nc = 0;
    for (int j = 0; j < v; ++j) cset[nc++] = j;
    for (int j = 5 + v; j < 11; ++j) cset[nc++] = j;
    for (int a = 0; a < nr; ++a) { br1 += E[rset[a]]; br2 += E[10 + rset[a]]; }
    for (int b = 0; b < nc; ++b) { bc1 += E[20 + cset[b]]; bc2 += E[31 + cset[b]]; }
    for (int a = 0; a < nr; ++a)
      for (int b = 0; b < nc; ++b) {
        x1 += E[42 + rset[a] * 11 + cset[b]];
        x2 += E[152 + rset[a] * 11 + cset[b]];
      }
    const double T1 = M[36], T2 = M[37];
    const double W1 = M[38] - br1 - bc1 + x1;
    const double W2 = M[39] - br2 - bc2 + x2;
    const double CCv = M[t];
    const double N = 32.0 * 378.0 * 378.0;
    const double S1 = T1 - W1;
    const double S2 = T2 - 2.0 * CCv + W2;
    loss[t] = S2 / N - (S1 / N) * (S1 / N);
  }
  __syncthreads();
  if (t == 0) {
    double best = loss[0];
    for (int o = 1; o < 36; ++o) best = fmin(best, loss[o]);
    out[0] = (float)(-10.0 * log10(best));
  }
}

extern "C" void kernel_launch(void* const* d_in, const int* in_sizes, int n_in,
                              void* d_out, int out_size, void* d_ws, size_t ws_size,
                              hipStream_t stream) {
  const float* predict = (const float*)d_in[0];
  const float* target  = (const float*)d_in[1];
  const float* mask    = (const float*)d_in[2];
  float* out = (float*)d_out;

  float*  mpart = (float*)d_ws;                               // 40*2304*4 = 368640 B
  double* epart = (double*)((char*)d_ws + NM * MSTRIDE * 4);  // 262*32*8  =  67072 B

  probav_fused_kernel<<<NTOT, 256, 0, stream>>>(predict, target, mask, mpart, epart);
  probav_final_kernel<<<1, 1024, 0, stream>>>(mpart, epart, out);
}

// Round 12
// 49.823 us; speedup vs baseline: 1.2246x; 1.2246x over previous
//
#include <hip/hip_runtime.h>
#include <hip/hip_bf16.h>
#include <math.h>

// ProbaV cPSNR:  loss(u,v) = E[d^2] - (E[d])^2,  d = ct - pm_window(u,v)
// S1(u,v) = T1 - W1(u,v);  S2(u,v) = T2 - 2*CC(u,v) + W2(u,v)
//   T1,T2   : sum ct, sum ct^2            (ct = target*mask, inner 378x378 @ +3)
//   CC(u,v) : sum ct[r][c] * pm[r+u][c+v] (pm = predict*mask)
//   W1,W2   : window sums of pm, pm^2 over rows [u,u+378) x cols [v,v+378)
// W = Total - BR(u) - BC(v) + X(u,v)  (inclusion-exclusion, rows 0..382 x cols 0..383)
//
// R11 = R8 (3-row x 8-col per-thread tiling, XCD swizzle, two dispatches)
// + explicit 2-deep register prefetch pipeline over the 8 pm rows.
// R3-R10 post-mortems: perf invariant ~42-55us across tilings/occupancy =>
// bound by waitcnt drain between dependent load batches (effective ~1.3 TB/s
// vs 2.1-2.4 TB/s observed for massively-parallel spill traffic). Prefetch
// R+1's 8 quad-loads before computing R keeps the VMEM pipe fed.

#define NIMG 32
#define IMGSZ (384 * 384)
#define NRT 126                  // row tiles (3 ct rows each)
#define NSG 48                   // col segments (8 cols)
#define NCC 756                  // cc blocks = 32*126*48/256
#define NEDGE 64                 // 2 per image
#define NTOT (NCC + NEDGE)       // 820 logical blocks
#define NPAD 824                 // padded grid: 8 * 103 (bijective swizzle)
#define CHUNK 103
#define NM 40                    // cc[36], t1, t2, tot1, tot2
#define MSTRIDE 756              // mpart col-major [NM][MSTRIDE]
#define MQUADS 189               // MSTRIDE/4
#define NE 262                   // edge entries per image

__global__ __launch_bounds__(256) void probav_fused_kernel(
    const float* __restrict__ predict,
    const float* __restrict__ target,
    const float* __restrict__ mask,
    float* __restrict__ mpart /* [NM][MSTRIDE] */,
    double* __restrict__ epart /* [NE][NIMG] */) {

  // XCD-chunked swizzle: bijective 0..823 -> 0..823 (824 = 8*103); pad blocks exit.
  const int lbid = (blockIdx.x & 7) * CHUNK + (blockIdx.x >> 3);
  if (lbid >= NTOT) return;

  __shared__ double shbuf[506];
  const int t = threadIdx.x;
  const int lane = t & 63;
  const int w = t >> 6;

  if (lbid >= NEDGE) {
    // ---------------- cc path: 3 ct rows x 8 cols per thread ----------------
    const int cb  = lbid - NEDGE;
    const int tid = cb * 256 + t;
    const int img = tid / (NRT * NSG);
    const int rem = tid - img * (NRT * NSG);
    const int rt  = rem / NSG;
    const int sg  = rem - rt * NSG;
    const int r0  = rt * 3;
    const int jb  = sg * 8;
    const size_t base = (size_t)img * IMGSZ;
    const bool isLastRt = (rt == NRT - 1);   // owns pm rows 375..382

    // ct tile: input rows r0+3..r0+5, cols jb+3..jb+10 via 3 aligned quads
    float ct[3][8];
    float t1 = 0.f, t2 = 0.f;
#pragma unroll
    for (int rr = 0; rr < 3; ++rr) {
      const float4* tq = reinterpret_cast<const float4*>(target + base + (size_t)(r0 + rr + 3) * 384 + jb);
      const float4* mq = reinterpret_cast<const float4*>(mask   + base + (size_t)(r0 + rr + 3) * 384 + jb);
      float tv[12], mv[12];
#pragma unroll
      for (int q = 0; q < 3; ++q) {
        float4 a = tq[q];
        float4 b = mq[q];
        tv[4 * q + 0] = a.x; tv[4 * q + 1] = a.y; tv[4 * q + 2] = a.z; tv[4 * q + 3] = a.w;
        mv[4 * q + 0] = b.x; mv[4 * q + 1] = b.y; mv[4 * q + 2] = b.z; mv[4 * q + 3] = b.w;
      }
#pragma unroll
      for (int x = 0; x < 8; ++x) {
        float v = tv[3 + x] * mv[3 + x];
        v = (jb + x < 378) ? v : 0.f;
        ct[rr][x] = v;
        t1 += v;
        t2 = fmaf(v, v, t2);
      }
    }

    float cc[36];
#pragma unroll
    for (int o = 0; o < 36; ++o) cc[o] = 0.f;
    float tot1 = 0.f, tot2 = 0.f;

    // ---- 2-deep prefetch pipeline over pm rows R = 0..7 ----
    // Buffer A and B: 4 p-quads + 4 m-quads each (named regs, static indices).
    float4 pA0, pA1, pA2, pA3, mA0, mA1, mA2, mA3;
    float4 pB0, pB1, pB2, pB3, mB0, mB1, mB2, mB3;

#define ISSUE_ROW(P0, P1, P2, P3, Q0, Q1, Q2, Q3, R)                                   \
    {                                                                                  \
      const float4* pq_ = reinterpret_cast<const float4*>(predict + base + (size_t)(r0 + (R)) * 384 + jb); \
      const float4* mq_ = reinterpret_cast<const float4*>(mask    + base + (size_t)(r0 + (R)) * 384 + jb); \
      P0 = pq_[0]; P1 = pq_[1]; P2 = pq_[2]; P3 = pq_[3];                              \
      Q0 = mq_[0]; Q1 = mq_[1]; Q2 = mq_[2]; Q3 = mq_[3];                              \
    }

#define COMPUTE_ROW(P0, P1, P2, P3, Q0, Q1, Q2, Q3, R)                                 \
    {                                                                                  \
      float pm[16];                                                                    \
      pm[0]  = P0.x * Q0.x; pm[1]  = P0.y * Q0.y; pm[2]  = P0.z * Q0.z; pm[3]  = P0.w * Q0.w; \
      pm[4]  = P1.x * Q1.x; pm[5]  = P1.y * Q1.y; pm[6]  = P1.z * Q1.z; pm[7]  = P1.w * Q1.w; \
      pm[8]  = P2.x * Q2.x; pm[9]  = P2.y * Q2.y; pm[10] = P2.z * Q2.z; pm[11] = P2.w * Q2.w; \
      pm[12] = P3.x * Q3.x; pm[13] = P3.y * Q3.y; pm[14] = P3.z * Q3.z; pm[15] = P3.w * Q3.w; \
      if ((R) < 3 || isLastRt) {                                                       \
        _Pragma("unroll")                                                              \
        for (int x = 0; x < 8; ++x) {                                                  \
          tot1 += pm[x];                                                               \
          tot2 = fmaf(pm[x], pm[x], tot2);                                             \
        }                                                                              \
      }                                                                                \
      {                                                                                \
        const int rlo = ((R) > 5) ? ((R) - 5) : 0;                                     \
        const int rhi = ((R) < 2) ? (R) : 2;                                           \
        _Pragma("unroll")                                                              \
        for (int rr = rlo; rr <= rhi; ++rr) {                                          \
          const int u = (R) - rr;                                                      \
          _Pragma("unroll")                                                            \
          for (int v = 0; v < 6; ++v) {                                                \
            _Pragma("unroll")                                                          \
            for (int x = 0; x < 8; ++x) {                                              \
              cc[u * 6 + v] = fmaf(ct[rr][x], pm[v + x], cc[u * 6 + v]);               \
            }                                                                          \
          }                                                                            \
        }                                                                              \
      }                                                                                \
    }

    ISSUE_ROW(pA0, pA1, pA2, pA3, mA0, mA1, mA2, mA3, 0)
    ISSUE_ROW(pB0, pB1, pB2, pB3, mB0, mB1, mB2, mB3, 1)
    COMPUTE_ROW(pA0, pA1, pA2, pA3, mA0, mA1, mA2, mA3, 0)
    ISSUE_ROW(pA0, pA1, pA2, pA3, mA0, mA1, mA2, mA3, 2)
    COMPUTE_ROW(pB0, pB1, pB2, pB3, mB0, mB1, mB2, mB3, 1)
    ISSUE_ROW(pB0, pB1, pB2, pB3, mB0, mB1, mB2, mB3, 3)
    COMPUTE_ROW(pA0, pA1, pA2, pA3, mA0, mA1, mA2, mA3, 2)
    ISSUE_ROW(pA0, pA1, pA2, pA3, mA0, mA1, mA2, mA3, 4)
    COMPUTE_ROW(pB0, pB1, pB2, pB3, mB0, mB1, mB2, mB3, 3)
    ISSUE_ROW(pB0, pB1, pB2, pB3, mB0, mB1, mB2, mB3, 5)
    COMPUTE_ROW(pA0, pA1, pA2, pA3, mA0, mA1, mA2, mA3, 4)
    ISSUE_ROW(pA0, pA1, pA2, pA3, mA0, mA1, mA2, mA3, 6)
    COMPUTE_ROW(pB0, pB1, pB2, pB3, mB0, mB1, mB2, mB3, 5)
    ISSUE_ROW(pB0, pB1, pB2, pB3, mB0, mB1, mB2, mB3, 7)
    COMPUTE_ROW(pA0, pA1, pA2, pA3, mA0, mA1, mA2, mA3, 6)
    COMPUTE_ROW(pB0, pB1, pB2, pB3, mB0, mB1, mB2, mB3, 7)

#undef ISSUE_ROW
#undef COMPUTE_ROW

    // block reduction: 40 floats -> mpart column-major
    float* red = reinterpret_cast<float*>(shbuf);  // [4][NM]
#pragma unroll
    for (int o = 0; o < 36; ++o) {
      float a = cc[o];
#pragma unroll
      for (int off = 32; off > 0; off >>= 1) a += __shfl_down(a, off);
      if (lane == 0) red[w * NM + o] = a;
    }
    {
      float a = t1, b = t2, c = tot1, d = tot2;
#pragma unroll
      for (int off = 32; off > 0; off >>= 1) {
        a += __shfl_down(a, off);
        b += __shfl_down(b, off);
        c += __shfl_down(c, off);
        d += __shfl_down(d, off);
      }
      if (lane == 0) { red[w * NM + 36] = a; red[w * NM + 37] = b; red[w * NM + 38] = c; red[w * NM + 39] = d; }
    }
    __syncthreads();
    if (t < NM) {
      float v = red[0 * NM + t] + red[1 * NM + t] + red[2 * NM + t] + red[3 * NM + t];
      mpart[t * MSTRIDE + cb] = v;
    }
  } else {
    // ---------------- edge path: 2 blocks per image ----------------
    const int img = lbid >> 1;
    const int slice = lbid & 1;
    const size_t base = (size_t)img * IMGSZ;
    double* sh = shbuf;

    if (slice == 0) {
      // full-row sums, rows {0..4, 378..382}, cols 0..383
      if (t < 250) {
        const int ridx = t / 25, cs = t % 25;
        const int row = (ridx < 5) ? ridx : (373 + ridx);
        const float* pr = predict + base + (size_t)row * 384;
        const float* mr = mask    + base + (size_t)row * 384;
        double e1 = 0.0, e2 = 0.0;
        for (int c = cs; c < 384; c += 25) {
          float v = pr[c] * mr[c];
          e1 += v;
          e2 += (double)v * v;
        }
        sh[ridx * 25 + cs] = e1;
        sh[250 + ridx * 25 + cs] = e2;
      }
      __syncthreads();
      if (t < 20) {
        const int kind = t / 10, ridx = t % 10;
        double s = 0.0;
        for (int k = 0; k < 25; ++k) s += sh[kind * 250 + ridx * 25 + k];
        epart[(size_t)(kind * 10 + ridx) * NIMG + img] = s;
      }
      // corner table 10x11
      if (t < 110) {
        const int ridx = t / 11, cidx = t % 11;
        const int row = (ridx < 5) ? ridx : (373 + ridx);
        const int col = (cidx < 5) ? cidx : (373 + cidx);
        float v = predict[base + (size_t)row * 384 + col] * mask[base + (size_t)row * 384 + col];
        epart[(size_t)(42 + t)  * NIMG + img] = (double)v;
        epart[(size_t)(152 + t) * NIMG + img] = (double)v * v;
      }
    } else {
      // full-col sums, cols {0..4, 378..383}, rows 0..382
      if (t < 253) {
        const int cidx = t / 23, rs = t % 23;
        const int col = (cidx < 5) ? cidx : (373 + cidx);
        double f1 = 0.0, f2 = 0.0;
        for (int r = rs; r < 383; r += 23) {
          float v = predict[base + (size_t)r * 384 + col] * mask[base + (size_t)r * 384 + col];
          f1 += v;
          f2 += (double)v * v;
        }
        sh[cidx * 23 + rs] = f1;
        sh[253 + cidx * 23 + rs] = f2;
      }
      __syncthreads();
      if (t < 22) {
        const int kind = t / 11, cidx = t % 11;
        double s = 0.0;
        for (int k = 0; k < 23; ++k) s += sh[kind * 253 + cidx * 23 + k];
        epart[(size_t)(20 + kind * 11 + cidx) * NIMG + img] = s;
      }
    }
  }
}

// ---------------- final kernel: assemble 36 losses, min, score ----------------
__global__ void probav_final_kernel(const float* __restrict__ mpart,
                                    const double* __restrict__ epart,
                                    float* __restrict__ out) {
  __shared__ double M[NM];
  __shared__ double E[NE];
  __shared__ double Etmp[524];
  __shared__ double loss[36];
  const int t = threadIdx.x;          // 1024 threads
  const int lane = t & 63;
  const int w = t >> 6;               // 16 waves

  // M: 40 columns; each column is MSTRIDE contiguous floats = MQUADS float4s
  for (int v = w; v < NM; v += 16) {
    const float4* qp = reinterpret_cast<const float4*>(mpart + v * MSTRIDE);
    double s = 0.0;
    for (int i = lane; i < MQUADS; i += 64) {
      float4 q = qp[i];
      s += (double)q.x + (double)q.y + (double)q.z + (double)q.w;
    }
#pragma unroll
    for (int off = 32; off > 0; off >>= 1) s += __shfl_down(s, off);
    if (lane == 0) M[v] = s;
  }
  // E: 262 entries x 32 contiguous doubles, 2 threads per entry
  if (t < 524) {
    const int e = t >> 1, si = t & 1;
    double s = 0.0;
    for (int i = si * 16; i < si * 16 + 16; ++i) s += epart[(size_t)e * NIMG + i];
    Etmp[t] = s;
  }
  __syncthreads();
  if (t < NE) E[t] = Etmp[2 * t] + Etmp[2 * t + 1];
  __syncthreads();

  if (t < 36) {
    const int u = t / 6, v = t % 6;
    double br1 = 0, br2 = 0, bc1 = 0, bc2 = 0, x1 = 0, x2 = 0;
    int rset[5], nr = 0;
    for (int j = 0; j < u; ++j) rset[nr++] = j;
    for (int j = 5 + u; j < 10; ++j) rset[nr++] = j;
    int cset[6], nc = 0;
    for (int j = 0; j < v; ++j) cset[nc++] = j;
    for (int j = 5 + v; j < 11; ++j) cset[nc++] = j;
    for (int a = 0; a < nr; ++a) { br1 += E[rset[a]]; br2 += E[10 + rset[a]]; }
    for (int b = 0; b < nc; ++b) { bc1 += E[20 + cset[b]]; bc2 += E[31 + cset[b]]; }
    for (int a = 0; a < nr; ++a)
      for (int b = 0; b < nc; ++b) {
        x1 += E[42 + rset[a] * 11 + cset[b]];
        x2 += E[152 + rset[a] * 11 + cset[b]];
      }
    const double T1 = M[36], T2 = M[37];
    const double W1 = M[38] - br1 - bc1 + x1;
    const double W2 = M[39] - br2 - bc2 + x2;
    const double CCv = M[t];
    const double N = 32.0 * 378.0 * 378.0;
    const double S1 = T1 - W1;
    const double S2 = T2 - 2.0 * CCv + W2;
    loss[t] = S2 / N - (S1 / N) * (S1 / N);
  }
  __syncthreads();
  if (t == 0) {
    double best = loss[0];
    for (int o = 1; o < 36; ++o) best = fmin(best, loss[o]);
    out[0] = (float)(-10.0 * log10(best));
  }
}

extern "C" void kernel_launch(void* const* d_in, const int* in_sizes, int n_in,
                              void* d_out, int out_size, void* d_ws, size_t ws_size,
                              hipStream_t stream) {
  const float* predict = (const float*)d_in[0];
  const float* target  = (const float*)d_in[1];
  const float* mask    = (const float*)d_in[2];
  float* out = (float*)d_out;

  float*  mpart = (float*)d_ws;                               // 40*756*4 = 120960 B
  double* epart = (double*)((char*)d_ws + NM * MSTRIDE * 4);  // 262*32*8 =  67072 B

  probav_fused_kernel<<<NPAD, 256, 0, stream>>>(predict, target, mask, mpart, epart);
  probav_final_kernel<<<1, 1024, 0, stream>>>(mpart, epart, out);
}

// Round 13
// 49.343 us; speedup vs baseline: 1.2366x; 1.0097x over previous
//
#include <hip/hip_runtime.h>
#include <hip/hip_bf16.h>
#include <math.h>

// ProbaV cPSNR:  loss(u,v) = E[d^2] - (E[d])^2,  d = ct - pm_window(u,v)
// S1(u,v) = T1 - W1(u,v);  S2(u,v) = T2 - 2*CC(u,v) + W2(u,v)
//   T1,T2   : sum ct, sum ct^2            (ct = target*mask, inner 378x378 @ +3)
//   CC(u,v) : sum ct[r][c] * pm[r+u][c+v] (pm = predict*mask)
//   W1,W2   : window sums of pm, pm^2 over rows [u,u+378) x cols [v,v+378)
// W = Total - BR(u) - BC(v) + X(u,v)  (inclusion-exclusion, rows 0..382 x cols 0..383)
//
// R13 = R11 cc core (3x8 tiling + 2-deep prefetch) with the straggler tail fixed:
//   - edge blocks at blockIdx 0..63 (natural mod-8 XCD round-robin, dispatched
//     first; previously the swizzle put ALL edge blocks on XCD 0);
//   - edge path wave-parallel (64-lane rows/cols, butterfly reduce, chain 6 not
//     16, no LDS, no barrier);
//   - cc blocks 64..823, bijective swizzle over 760 = 8*95.

#define NIMG 32
#define IMGSZ (384 * 384)
#define NRT 126                  // row tiles (3 ct rows each)
#define NSG 48                   // col segments (8 cols)
#define NCC 756                  // cc blocks = 32*126*48/256
#define NEDGE 64                 // 2 per image, blockIdx 0..63
#define CCPAD 760                // 8 * 95 (bijective swizzle domain)
#define CHUNK 95
#define NM 40                    // cc[36], t1, t2, tot1, tot2
#define MSTRIDE 756              // mpart col-major [NM][MSTRIDE]
#define MQUADS 189               // MSTRIDE/4
#define NE 262                   // edge entries per image

__global__ __launch_bounds__(256) void probav_fused_kernel(
    const float* __restrict__ predict,
    const float* __restrict__ target,
    const float* __restrict__ mask,
    float* __restrict__ mpart /* [NM][MSTRIDE] */,
    double* __restrict__ epart /* [NE][NIMG] */) {

  const int t = threadIdx.x;
  const int lane = t & 63;
  const int w = t >> 6;

  if (blockIdx.x >= NEDGE) {
    // ---------------- cc path: 3 ct rows x 8 cols per thread ----------------
    const int i = blockIdx.x - NEDGE;
    const int cb = (i & 7) * CHUNK + (i >> 3);   // bijective on 760; 756..759 pad
    if (cb >= NCC) return;

    __shared__ float red[4 * NM];

    const int tid = cb * 256 + t;
    const int img = tid / (NRT * NSG);
    const int rem = tid - img * (NRT * NSG);
    const int rt  = rem / NSG;
    const int sg  = rem - rt * NSG;
    const int r0  = rt * 3;
    const int jb  = sg * 8;
    const size_t base = (size_t)img * IMGSZ;
    const bool isLastRt = (rt == NRT - 1);   // owns pm rows 375..382

    // ct tile: input rows r0+3..r0+5, cols jb+3..jb+10 via 3 aligned quads
    float ct[3][8];
    float t1 = 0.f, t2 = 0.f;
#pragma unroll
    for (int rr = 0; rr < 3; ++rr) {
      const float4* tq = reinterpret_cast<const float4*>(target + base + (size_t)(r0 + rr + 3) * 384 + jb);
      const float4* mq = reinterpret_cast<const float4*>(mask   + base + (size_t)(r0 + rr + 3) * 384 + jb);
      float tv[12], mv[12];
#pragma unroll
      for (int q = 0; q < 3; ++q) {
        float4 a = tq[q];
        float4 b = mq[q];
        tv[4 * q + 0] = a.x; tv[4 * q + 1] = a.y; tv[4 * q + 2] = a.z; tv[4 * q + 3] = a.w;
        mv[4 * q + 0] = b.x; mv[4 * q + 1] = b.y; mv[4 * q + 2] = b.z; mv[4 * q + 3] = b.w;
      }
#pragma unroll
      for (int x = 0; x < 8; ++x) {
        float v = tv[3 + x] * mv[3 + x];
        v = (jb + x < 378) ? v : 0.f;
        ct[rr][x] = v;
        t1 += v;
        t2 = fmaf(v, v, t2);
      }
    }

    float cc[36];
#pragma unroll
    for (int o = 0; o < 36; ++o) cc[o] = 0.f;
    float tot1 = 0.f, tot2 = 0.f;

    // ---- 2-deep prefetch pipeline over pm rows R = 0..7 ----
    float4 pA0, pA1, pA2, pA3, mA0, mA1, mA2, mA3;
    float4 pB0, pB1, pB2, pB3, mB0, mB1, mB2, mB3;

#define ISSUE_ROW(P0, P1, P2, P3, Q0, Q1, Q2, Q3, R)                                   \
    {                                                                                  \
      const float4* pq_ = reinterpret_cast<const float4*>(predict + base + (size_t)(r0 + (R)) * 384 + jb); \
      const float4* mq_ = reinterpret_cast<const float4*>(mask    + base + (size_t)(r0 + (R)) * 384 + jb); \
      P0 = pq_[0]; P1 = pq_[1]; P2 = pq_[2]; P3 = pq_[3];                              \
      Q0 = mq_[0]; Q1 = mq_[1]; Q2 = mq_[2]; Q3 = mq_[3];                              \
    }

#define COMPUTE_ROW(P0, P1, P2, P3, Q0, Q1, Q2, Q3, R)                                 \
    {                                                                                  \
      float pm[16];                                                                    \
      pm[0]  = P0.x * Q0.x; pm[1]  = P0.y * Q0.y; pm[2]  = P0.z * Q0.z; pm[3]  = P0.w * Q0.w; \
      pm[4]  = P1.x * Q1.x; pm[5]  = P1.y * Q1.y; pm[6]  = P1.z * Q1.z; pm[7]  = P1.w * Q1.w; \
      pm[8]  = P2.x * Q2.x; pm[9]  = P2.y * Q2.y; pm[10] = P2.z * Q2.z; pm[11] = P2.w * Q2.w; \
      pm[12] = P3.x * Q3.x; pm[13] = P3.y * Q3.y; pm[14] = P3.z * Q3.z; pm[15] = P3.w * Q3.w; \
      if ((R) < 3 || isLastRt) {                                                       \
        _Pragma("unroll")                                                              \
        for (int x = 0; x < 8; ++x) {                                                  \
          tot1 += pm[x];                                                               \
          tot2 = fmaf(pm[x], pm[x], tot2);                                             \
        }                                                                              \
      }                                                                                \
      {                                                                                \
        const int rlo = ((R) > 5) ? ((R) - 5) : 0;                                     \
        const int rhi = ((R) < 2) ? (R) : 2;                                           \
        _Pragma("unroll")                                                              \
        for (int rr = rlo; rr <= rhi; ++rr) {                                          \
          const int u = (R) - rr;                                                      \
          _Pragma("unroll")                                                            \
          for (int v = 0; v < 6; ++v) {                                                \
            _Pragma("unroll")                                                          \
            for (int x = 0; x < 8; ++x) {                                              \
              cc[u * 6 + v] = fmaf(ct[rr][x], pm[v + x], cc[u * 6 + v]);               \
            }                                                                          \
          }                                                                            \
        }                                                                              \
      }                                                                                \
    }

    ISSUE_ROW(pA0, pA1, pA2, pA3, mA0, mA1, mA2, mA3, 0)
    ISSUE_ROW(pB0, pB1, pB2, pB3, mB0, mB1, mB2, mB3, 1)
    COMPUTE_ROW(pA0, pA1, pA2, pA3, mA0, mA1, mA2, mA3, 0)
    ISSUE_ROW(pA0, pA1, pA2, pA3, mA0, mA1, mA2, mA3, 2)
    COMPUTE_ROW(pB0, pB1, pB2, pB3, mB0, mB1, mB2, mB3, 1)
    ISSUE_ROW(pB0, pB1, pB2, pB3, mB0, mB1, mB2, mB3, 3)
    COMPUTE_ROW(pA0, pA1, pA2, pA3, mA0, mA1, mA2, mA3, 2)
    ISSUE_ROW(pA0, pA1, pA2, pA3, mA0, mA1, mA2, mA3, 4)
    COMPUTE_ROW(pB0, pB1, pB2, pB3, mB0, mB1, mB2, mB3, 3)
    ISSUE_ROW(pB0, pB1, pB2, pB3, mB0, mB1, mB2, mB3, 5)
    COMPUTE_ROW(pA0, pA1, pA2, pA3, mA0, mA1, mA2, mA3, 4)
    ISSUE_ROW(pA0, pA1, pA2, pA3, mA0, mA1, mA2, mA3, 6)
    COMPUTE_ROW(pB0, pB1, pB2, pB3, mB0, mB1, mB2, mB3, 5)
    ISSUE_ROW(pB0, pB1, pB2, pB3, mB0, mB1, mB2, mB3, 7)
    COMPUTE_ROW(pA0, pA1, pA2, pA3, mA0, mA1, mA2, mA3, 6)
    COMPUTE_ROW(pB0, pB1, pB2, pB3, mB0, mB1, mB2, mB3, 7)

#undef ISSUE_ROW
#undef COMPUTE_ROW

    // block reduction: 40 floats -> mpart column-major
#pragma unroll
    for (int o = 0; o < 36; ++o) {
      float a = cc[o];
#pragma unroll
      for (int off = 32; off > 0; off >>= 1) a += __shfl_down(a, off);
      if (lane == 0) red[w * NM + o] = a;
    }
    {
      float a = t1, b = t2, c = tot1, d = tot2;
#pragma unroll
      for (int off = 32; off > 0; off >>= 1) {
        a += __shfl_down(a, off);
        b += __shfl_down(b, off);
        c += __shfl_down(c, off);
        d += __shfl_down(d, off);
      }
      if (lane == 0) { red[w * NM + 36] = a; red[w * NM + 37] = b; red[w * NM + 38] = c; red[w * NM + 39] = d; }
    }
    __syncthreads();
    if (t < NM) {
      float v = red[0 * NM + t] + red[1 * NM + t] + red[2 * NM + t] + red[3 * NM + t];
      mpart[t * MSTRIDE + cb] = v;
    }
  } else {
    // ---------------- edge path: blockIdx 0..63, wave-parallel, no LDS ----------------
    const int img = blockIdx.x >> 1;
    const int slice = blockIdx.x & 1;
    const size_t base = (size_t)img * IMGSZ;

    if (slice == 0) {
      // full-row sums, rows {0..4, 378..382}: wave w handles ridx w, w+4, w+8
      for (int ridx = w; ridx < 10; ridx += 4) {
        const int row = (ridx < 5) ? ridx : (373 + ridx);
        const float* pr = predict + base + (size_t)row * 384;
        const float* mr = mask    + base + (size_t)row * 384;
        double e1 = 0.0, e2 = 0.0;
#pragma unroll
        for (int k = 0; k < 6; ++k) {
          float v = pr[lane + 64 * k] * mr[lane + 64 * k];
          e1 += v;
          e2 += (double)v * v;
        }
#pragma unroll
        for (int off = 32; off > 0; off >>= 1) {
          e1 += __shfl_down(e1, off);
          e2 += __shfl_down(e2, off);
        }
        if (lane == 0) {
          epart[(size_t)ridx        * NIMG + img] = e1;
          epart[(size_t)(10 + ridx) * NIMG + img] = e2;
        }
      }
      // corner table 10x11
      if (t < 110) {
        const int ridx = t / 11, cidx = t % 11;
        const int row = (ridx < 5) ? ridx : (373 + ridx);
        const int col = (cidx < 5) ? cidx : (373 + cidx);
        float v = predict[base + (size_t)row * 384 + col] * mask[base + (size_t)row * 384 + col];
        epart[(size_t)(42 + t)  * NIMG + img] = (double)v;
        epart[(size_t)(152 + t) * NIMG + img] = (double)v * v;
      }
    } else {
      // full-col sums, cols {0..4, 378..383}, rows 0..382: wave w -> cidx w, w+4, w+8
      for (int cidx = w; cidx < 11; cidx += 4) {
        const int col = (cidx < 5) ? cidx : (373 + cidx);
        double f1 = 0.0, f2 = 0.0;
#pragma unroll
        for (int k = 0; k < 6; ++k) {
          const int r = lane + 64 * k;
          if (r < 383) {
            float v = predict[base + (size_t)r * 384 + col] * mask[base + (size_t)r * 384 + col];
            f1 += v;
            f2 += (double)v * v;
          }
        }
#pragma unroll
        for (int off = 32; off > 0; off >>= 1) {
          f1 += __shfl_down(f1, off);
          f2 += __shfl_down(f2, off);
        }
        if (lane == 0) {
          epart[(size_t)(20 + cidx) * NIMG + img] = f1;
          epart[(size_t)(31 + cidx) * NIMG + img] = f2;
        }
      }
    }
  }
}

// ---------------- final kernel: assemble 36 losses, min, score ----------------
__global__ void probav_final_kernel(const float* __restrict__ mpart,
                                    const double* __restrict__ epart,
                                    float* __restrict__ out) {
  __shared__ double M[NM];
  __shared__ double E[NE];
  __shared__ double Etmp[524];
  __shared__ double loss[36];
  const int t = threadIdx.x;          // 1024 threads
  const int lane = t & 63;
  const int w = t >> 6;               // 16 waves

  // M: 40 columns; each column is MSTRIDE contiguous floats = MQUADS float4s
  for (int v = w; v < NM; v += 16) {
    const float4* qp = reinterpret_cast<const float4*>(mpart + v * MSTRIDE);
    double s = 0.0;
    for (int i = lane; i < MQUADS; i += 64) {
      float4 q = qp[i];
      s += (double)q.x + (double)q.y + (double)q.z + (double)q.w;
    }
#pragma unroll
    for (int off = 32; off > 0; off >>= 1) s += __shfl_down(s, off);
    if (lane == 0) M[v] = s;
  }
  // E: 262 entries x 32 contiguous doubles, 2 threads per entry
  if (t < 524) {
    const int e = t >> 1, si = t & 1;
    double s = 0.0;
    for (int i = si * 16; i < si * 16 + 16; ++i) s += epart[(size_t)e * NIMG + i];
    Etmp[t] = s;
  }
  __syncthreads();
  if (t < NE) E[t] = Etmp[2 * t] + Etmp[2 * t + 1];
  __syncthreads();

  if (t < 36) {
    const int u = t / 6, v = t % 6;
    double br1 = 0, br2 = 0, bc1 = 0, bc2 = 0, x1 = 0, x2 = 0;
    int rset[5], nr = 0;
    for (int j = 0; j < u; ++j) rset[nr++] = j;
    for (int j = 5 + u; j < 10; ++j) rset[nr++] = j;
    int cset[6], nc = 0;
    for (int j = 0; j < v; ++j) cset[nc++] = j;
    for (int j = 5 + v; j < 11; ++j) cset[nc++] = j;
    for (int a = 0; a < nr; ++a) { br1 += E[rset[a]]; br2 += E[10 + rset[a]]; }
    for (int b = 0; b < nc; ++b) { bc1 += E[20 + cset[b]]; bc2 += E[31 + cset[b]]; }
    for (int a = 0; a < nr; ++a)
      for (int b = 0; b < nc; ++b) {
        x1 += E[42 + rset[a] * 11 + cset[b]];
        x2 += E[152 + rset[a] * 11 + cset[b]];
      }
    const double T1 = M[36], T2 = M[37];
    const double W1 = M[38] - br1 - bc1 + x1;
    const double W2 = M[39] - br2 - bc2 + x2;
    const double CCv = M[t];
    const double N = 32.0 * 378.0 * 378.0;
    const double S1 = T1 - W1;
    const double S2 = T2 - 2.0 * CCv + W2;
    loss[t] = S2 / N - (S1 / N) * (S1 / N);
  }
  __syncthreads();
  if (t == 0) {
    double best = loss[0];
    for (int o = 1; o < 36; ++o) best = fmin(best, loss[o]);
    out[0] = (float)(-10.0 * log10(best));
  }
}

extern "C" void kernel_launch(void* const* d_in, const int* in_sizes, int n_in,
                              void* d_out, int out_size, void* d_ws, size_t ws_size,
                              hipStream_t stream) {
  const float* predict = (const float*)d_in[0];
  const float* target  = (const float*)d_in[1];
  const float* mask    = (const float*)d_in[2];
  float* out = (float*)d_out;

  float*  mpart = (float*)d_ws;                               // 40*756*4 = 120960 B
  double* epart = (double*)((char*)d_ws + NM * MSTRIDE * 4);  // 262*32*8 =  67072 B

  probav_fused_kernel<<<NEDGE + CCPAD, 256, 0, stream>>>(predict, target, mask, mpart, epart);
  probav_final_kernel<<<1, 1024, 0, stream>>>(mpart, epart, out);
}